// Round 1
// baseline (180.060 us; speedup 1.0000x reference)
//
#include <hip/hip_runtime.h>

#define BB 8
#define SS 4096
#define DD 256
#define HH 1024
#define VOCAB 32000

// ws layout (floats):
//   esum : [B][D]  @ 0      (2048)   -- zeroed each call
//   u    : [B][D]  @ 2048   (2048)   -- zeroed each call
//   a    : [B][D]  @ 4096   (2048)
//   h    : [B][H]  @ 6144   (8192)
// logits go directly into d_out (softmax done in-place).

// Pass 1: esum[b,d] = sum_s (x!=0 ? emb[x,d] : 0)
__global__ void k_esum(const int* __restrict__ x, const float* __restrict__ emb,
                       float* __restrict__ esum) {
    __shared__ int toks[64];
    const int b = blockIdx.y;
    const int chunk = blockIdx.x;      // 64 chunks of 64 tokens
    const int tid = threadIdx.x;       // 256 threads = d index
    if (tid < 64) toks[tid] = x[b * SS + chunk * 64 + tid];
    __syncthreads();
    float a0 = 0.f, a1 = 0.f, a2 = 0.f, a3 = 0.f;
    for (int t = 0; t < 64; t += 4) {
        int t0 = toks[t], t1 = toks[t + 1], t2 = toks[t + 2], t3 = toks[t + 3];
        if (t0) a0 += emb[t0 * DD + tid];
        if (t1) a1 += emb[t1 * DD + tid];
        if (t2) a2 += emb[t2 * DD + tid];
        if (t3) a3 += emb[t3 * DD + tid];
    }
    atomicAdd(&esum[b * DD + tid], (a0 + a1) + (a2 + a3));
}

// a[b] = wk^T (wq @ esum[b])
__global__ void k_qsum_a(const float* __restrict__ esum, const float* __restrict__ wq,
                         const float* __restrict__ wk, float* __restrict__ a) {
    const int b = blockIdx.x, tid = threadIdx.x;
    __shared__ float es[DD], qs[DD];
    es[tid] = esum[b * DD + tid];
    __syncthreads();
    float acc = 0.f;
    for (int d = 0; d < DD; ++d) acc += wq[tid * DD + d] * es[d];   // qsum[e]
    qs[tid] = acc;
    __syncthreads();
    acc = 0.f;
    for (int e = 0; e < DD; ++e) acc += wk[e * DD + tid] * qs[e];   // a[p]
    a[b * DD + tid] = acc;
}

// Pass 2: u[b,d] = sum_s (a[b]·e_s) e_s[d]
__global__ void k_u(const int* __restrict__ x, const float* __restrict__ emb,
                    const float* __restrict__ a, float* __restrict__ u) {
    const int b = blockIdx.y;
    const int chunk = blockIdx.x;      // 64 chunks of 64 tokens
    const int tid = threadIdx.x;
    const int wid = tid >> 6, lane = tid & 63;
    __shared__ int toks[64];
    __shared__ float ured[4][DD];
    if (tid < 64) toks[tid] = x[b * SS + chunk * 64 + tid];
    __syncthreads();
    const float4 a4 = ((const float4*)(a + b * DD))[lane];
    float4 up = {0.f, 0.f, 0.f, 0.f};
    for (int t = wid; t < 64; t += 4) {       // each wave owns 16 tokens
        const int tok = toks[t];
        if (tok == 0) continue;               // pad row contributes nothing
        const float4 e4 = ((const float4*)(emb + tok * DD))[lane];
        float dp = e4.x * a4.x + e4.y * a4.y + e4.z * a4.z + e4.w * a4.w;
        #pragma unroll
        for (int off = 32; off; off >>= 1) dp += __shfl_xor(dp, off, 64);
        up.x += dp * e4.x; up.y += dp * e4.y; up.z += dp * e4.z; up.w += dp * e4.w;
    }
    ((float4*)ured[wid])[lane] = up;
    __syncthreads();
    {
        float s = ured[0][tid] + ured[1][tid] + ured[2][tid] + ured[3][tid];
        atomicAdd(&u[b * DD + tid], s);
    }
}

// v_out = wv @ u ; h = relu(w1 @ v_out + b1)
__global__ void k_vout_h(const float* __restrict__ u, const float* __restrict__ wv,
                         const float* __restrict__ w1, const float* __restrict__ b1,
                         float* __restrict__ h) {
    const int b = blockIdx.x, tid = threadIdx.x;
    __shared__ float us[DD], vo[DD];
    us[tid] = u[b * DD + tid];
    __syncthreads();
    float acc = 0.f;
    for (int q = 0; q < DD; ++q) acc += wv[tid * DD + q] * us[q];
    vo[tid] = acc;
    __syncthreads();
    #pragma unroll
    for (int r = 0; r < 4; ++r) {
        const int k = r * 256 + tid;
        float acc2 = b1[k];
        for (int e = 0; e < DD; ++e) acc2 += w1[k * DD + e] * vo[e];
        h[b * HH + k] = fmaxf(acc2, 0.f);
    }
}

// logits[b,i] = h[b]·w2[i] + b2[i]  -> written to d_out (pre-softmax)
__global__ __launch_bounds__(256) void k_logits(const float* __restrict__ h,
        const float* __restrict__ w2, const float* __restrict__ b2,
        float* __restrict__ logits) {
    const int tid = threadIdx.x, wid = tid >> 6, lane = tid & 63;
    // preload h into registers: hr[b][c] covers k = c*256 + lane*4 .. +3
    float4 hr[BB][4];
    #pragma unroll
    for (int b = 0; b < BB; ++b)
        #pragma unroll
        for (int c = 0; c < 4; ++c)
            hr[b][c] = ((const float4*)(h + b * HH + c * 256))[lane];
    const int wglobal = blockIdx.x * 4 + wid;   // 0..7999
    #pragma unroll
    for (int r = 0; r < 4; ++r) {
        const int i = wglobal + r * 8000;
        const float4* row = (const float4*)(w2 + (size_t)i * HH);
        float acc[BB];
        #pragma unroll
        for (int b = 0; b < BB; ++b) acc[b] = 0.f;
        #pragma unroll
        for (int c = 0; c < 4; ++c) {
            const float4 w = row[c * 64 + lane];
            #pragma unroll
            for (int b = 0; b < BB; ++b) {
                acc[b] += w.x * hr[b][c].x + w.y * hr[b][c].y +
                          w.z * hr[b][c].z + w.w * hr[b][c].w;
            }
        }
        #pragma unroll
        for (int b = 0; b < BB; ++b) {
            #pragma unroll
            for (int off = 32; off; off >>= 1) acc[b] += __shfl_xor(acc[b], off, 64);
        }
        if (lane < BB) logits[lane * VOCAB + i] = acc[lane] + b2[i];
    }
}

// softmax in-place over d_out rows
__global__ void k_softmax(float* __restrict__ out) {
    const int b = blockIdx.x, tid = threadIdx.x;
    __shared__ float red[256];
    float* lg = out + b * VOCAB;
    float m = -1e30f;
    for (int i = tid; i < VOCAB; i += 256) m = fmaxf(m, lg[i]);
    red[tid] = m; __syncthreads();
    for (int s = 128; s; s >>= 1) { if (tid < s) red[tid] = fmaxf(red[tid], red[tid + s]); __syncthreads(); }
    m = red[0]; __syncthreads();
    float sum = 0.f;
    for (int i = tid; i < VOCAB; i += 256) sum += __expf(lg[i] - m);
    red[tid] = sum; __syncthreads();
    for (int s = 128; s; s >>= 1) { if (tid < s) red[tid] += red[tid + s]; __syncthreads(); }
    const float inv = 1.f / red[0];
    for (int i = tid; i < VOCAB; i += 256) {
        const float v = __expf(lg[i] - m) * inv;
        lg[i] = v;
    }
}

extern "C" void kernel_launch(void* const* d_in, const int* in_sizes, int n_in,
                              void* d_out, int out_size, void* d_ws, size_t ws_size,
                              hipStream_t stream) {
    const int*   x   = (const int*)d_in[0];
    const float* emb = (const float*)d_in[1];
    const float* wq  = (const float*)d_in[2];
    const float* wk  = (const float*)d_in[3];
    const float* wv  = (const float*)d_in[4];
    const float* w1  = (const float*)d_in[5];
    const float* b1  = (const float*)d_in[6];
    const float* w2  = (const float*)d_in[7];
    const float* b2  = (const float*)d_in[8];
    float* out = (float*)d_out;
    float* ws  = (float*)d_ws;

    float* esum = ws;            // 2048
    float* u    = ws + 2048;     // 2048
    float* a    = ws + 4096;     // 2048
    float* h    = ws + 6144;     // 8192

    hipMemsetAsync(esum, 0, 4096 * sizeof(float), stream);   // esum + u

    k_esum<<<dim3(64, BB), 256, 0, stream>>>(x, emb, esum);
    k_qsum_a<<<BB, 256, 0, stream>>>(esum, wq, wk, a);
    k_u<<<dim3(64, BB), 256, 0, stream>>>(x, emb, a, u);
    k_vout_h<<<BB, 256, 0, stream>>>(u, wv, w1, b1, h);
    k_logits<<<2000, 256, 0, stream>>>(h, w2, b2, out);
    k_softmax<<<BB, 256, 0, stream>>>(out);
}

// Round 2
// 135.158 us; speedup vs baseline: 1.3322x; 1.3322x over previous
//
#include <hip/hip_runtime.h>

#define BB 8
#define SS 4096
#define DD 256
#define HH 1024
#define VOCAB 32000

// ws layout (floats), no zero-init required anywhere:
//   part_esum : [B][64][D] @ 0       (131072)
//   part_u    : [B][64][D] @ 131072  (131072)
//   a         : [B][D]     @ 262144  (2048)
//   h         : [B][H]     @ 264192  (8192)
//   spart     : [B][16][2] @ 272384  (256)   -- softmax partial (m, s)
// logits go directly into d_out (normalized in-place by k_norm).

// Pass 1: part_esum[b,chunk,d] = sum over 64 tokens of (x!=0 ? emb[x,d] : 0)
__global__ void k_esum(const int* __restrict__ x, const float* __restrict__ emb,
                       float* __restrict__ part_esum) {
    __shared__ int toks[64];
    const int b = blockIdx.y;
    const int chunk = blockIdx.x;      // 64 chunks of 64 tokens
    const int tid = threadIdx.x;       // 256 threads = d index
    if (tid < 64) toks[tid] = x[b * SS + chunk * 64 + tid];
    __syncthreads();
    float a0 = 0.f, a1 = 0.f, a2 = 0.f, a3 = 0.f;
    for (int t = 0; t < 64; t += 4) {
        int t0 = toks[t], t1 = toks[t + 1], t2 = toks[t + 2], t3 = toks[t + 3];
        if (t0) a0 += emb[t0 * DD + tid];
        if (t1) a1 += emb[t1 * DD + tid];
        if (t2) a2 += emb[t2 * DD + tid];
        if (t3) a3 += emb[t3 * DD + tid];
    }
    part_esum[(b * 64 + chunk) * DD + tid] = (a0 + a1) + (a2 + a3);
}

// esum[b] = reduce(part_esum); a[b] = wk^T (wq @ esum[b])
__global__ void k_qsum_a(const float* __restrict__ part_esum, const float* __restrict__ wq,
                         const float* __restrict__ wk, float* __restrict__ a) {
    const int b = blockIdx.x, tid = threadIdx.x;
    __shared__ float es[DD], qs[DD];
    {
        float s = 0.f;
        const float* p = part_esum + b * 64 * DD + tid;
        #pragma unroll 8
        for (int c = 0; c < 64; ++c) s += p[c * DD];
        es[tid] = s;
    }
    __syncthreads();
    float acc = 0.f;
    for (int d = 0; d < DD; ++d) acc += wq[tid * DD + d] * es[d];   // qsum[e]
    qs[tid] = acc;
    __syncthreads();
    acc = 0.f;
    for (int e = 0; e < DD; ++e) acc += wk[e * DD + tid] * qs[e];   // a[p]
    a[b * DD + tid] = acc;
}

// Pass 2: part_u[b,chunk,d] = sum over 64 tokens of (a[b]·e_s) e_s[d]
__global__ void k_u(const int* __restrict__ x, const float* __restrict__ emb,
                    const float* __restrict__ a, float* __restrict__ part_u) {
    const int b = blockIdx.y;
    const int chunk = blockIdx.x;      // 64 chunks of 64 tokens
    const int tid = threadIdx.x;
    const int wid = tid >> 6, lane = tid & 63;
    __shared__ int toks[64];
    __shared__ float ured[4][DD];
    if (tid < 64) toks[tid] = x[b * SS + chunk * 64 + tid];
    __syncthreads();
    const float4 a4 = ((const float4*)(a + b * DD))[lane];
    float4 up = {0.f, 0.f, 0.f, 0.f};
    for (int t = wid; t < 64; t += 4) {       // each wave owns 16 tokens
        const int tok = toks[t];
        if (tok == 0) continue;               // pad row contributes nothing
        const float4 e4 = ((const float4*)(emb + tok * DD))[lane];
        float dp = e4.x * a4.x + e4.y * a4.y + e4.z * a4.z + e4.w * a4.w;
        #pragma unroll
        for (int off = 32; off; off >>= 1) dp += __shfl_xor(dp, off, 64);
        up.x += dp * e4.x; up.y += dp * e4.y; up.z += dp * e4.z; up.w += dp * e4.w;
    }
    ((float4*)ured[wid])[lane] = up;
    __syncthreads();
    part_u[(b * 64 + chunk) * DD + tid] =
        ured[0][tid] + ured[1][tid] + ured[2][tid] + ured[3][tid];
}

// u = reduce(part_u); v_out = wv @ u ; h = relu(w1 @ v_out + b1)
__global__ void k_vout_h(const float* __restrict__ part_u, const float* __restrict__ wv,
                         const float* __restrict__ w1, const float* __restrict__ b1,
                         float* __restrict__ h) {
    const int b = blockIdx.x, tid = threadIdx.x;
    __shared__ float us[DD], vo[DD];
    {
        float s = 0.f;
        const float* p = part_u + b * 64 * DD + tid;
        #pragma unroll 8
        for (int c = 0; c < 64; ++c) s += p[c * DD];
        us[tid] = s;
    }
    __syncthreads();
    float acc = 0.f;
    for (int q = 0; q < DD; ++q) acc += wv[tid * DD + q] * us[q];
    vo[tid] = acc;
    __syncthreads();
    #pragma unroll
    for (int r = 0; r < 4; ++r) {
        const int k = r * 256 + tid;
        float acc2 = b1[k];
        for (int e = 0; e < DD; ++e) acc2 += w1[k * DD + e] * vo[e];
        h[b * HH + k] = fmaxf(acc2, 0.f);
    }
}

// logits[b,i] = h[b]·w2[i] + b2[i]  -> written to d_out (pre-softmax)
__global__ __launch_bounds__(256) void k_logits(const float* __restrict__ h,
        const float* __restrict__ w2, const float* __restrict__ b2,
        float* __restrict__ logits) {
    const int tid = threadIdx.x, wid = tid >> 6, lane = tid & 63;
    // preload h into registers: hr[b][c] covers k = c*256 + lane*4 .. +3
    float4 hr[BB][4];
    #pragma unroll
    for (int b = 0; b < BB; ++b)
        #pragma unroll
        for (int c = 0; c < 4; ++c)
            hr[b][c] = ((const float4*)(h + b * HH + c * 256))[lane];
    const int wglobal = blockIdx.x * 4 + wid;   // 0..7999
    #pragma unroll
    for (int r = 0; r < 4; ++r) {
        const int i = wglobal + r * 8000;
        const float4* row = (const float4*)(w2 + (size_t)i * HH);
        float acc[BB];
        #pragma unroll
        for (int b = 0; b < BB; ++b) acc[b] = 0.f;
        #pragma unroll
        for (int c = 0; c < 4; ++c) {
            const float4 w = row[c * 64 + lane];
            #pragma unroll
            for (int b = 0; b < BB; ++b) {
                acc[b] += w.x * hr[b][c].x + w.y * hr[b][c].y +
                          w.z * hr[b][c].z + w.w * hr[b][c].w;
            }
        }
        #pragma unroll
        for (int b = 0; b < BB; ++b) {
            #pragma unroll
            for (int off = 32; off; off >>= 1) acc[b] += __shfl_xor(acc[b], off, 64);
        }
        if (lane < BB) logits[lane * VOCAB + i] = acc[lane] + b2[i];
    }
}

// softmax stage 1: per-(batch, 1/16-slice) partial max + sumexp
__global__ void k_smax1(const float* __restrict__ logits, float* __restrict__ spart) {
    const int b = blockIdx.y, seg = blockIdx.x, tid = threadIdx.x;
    __shared__ float red[256];
    const float* lg = logits + b * VOCAB + seg * 2000;
    float m = -1e30f;
    for (int i = tid; i < 2000; i += 256) m = fmaxf(m, lg[i]);
    red[tid] = m; __syncthreads();
    for (int s = 128; s; s >>= 1) { if (tid < s) red[tid] = fmaxf(red[tid], red[tid + s]); __syncthreads(); }
    m = red[0]; __syncthreads();
    float sum = 0.f;
    for (int i = tid; i < 2000; i += 256) sum += __expf(lg[i] - m);
    red[tid] = sum; __syncthreads();
    for (int s = 128; s; s >>= 1) { if (tid < s) red[tid] += red[tid + s]; __syncthreads(); }
    if (tid == 0) {
        spart[b * 32 + seg * 2]     = m;
        spart[b * 32 + seg * 2 + 1] = red[0];
    }
}

// softmax stage 2: each block re-reduces the 16 partials, then normalizes its slice
__global__ void k_norm(const float* __restrict__ spart, float* __restrict__ out) {
    const int b = blockIdx.y, seg = blockIdx.x, tid = threadIdx.x;
    __shared__ float pm[16], ps[16], bm, binv;
    if (tid < 16) { pm[tid] = spart[b * 32 + tid * 2]; ps[tid] = spart[b * 32 + tid * 2 + 1]; }
    __syncthreads();
    if (tid == 0) {
        float m = pm[0];
        #pragma unroll
        for (int i = 1; i < 16; ++i) m = fmaxf(m, pm[i]);
        float s = 0.f;
        #pragma unroll
        for (int i = 0; i < 16; ++i) s += ps[i] * __expf(pm[i] - m);
        bm = m; binv = 1.f / s;
    }
    __syncthreads();
    const float m = bm, inv = binv;
    float* lg = out + b * VOCAB + seg * 2000;
    for (int i = tid; i < 2000; i += 256) lg[i] = __expf(lg[i] - m) * inv;
}

extern "C" void kernel_launch(void* const* d_in, const int* in_sizes, int n_in,
                              void* d_out, int out_size, void* d_ws, size_t ws_size,
                              hipStream_t stream) {
    const int*   x   = (const int*)d_in[0];
    const float* emb = (const float*)d_in[1];
    const float* wq  = (const float*)d_in[2];
    const float* wk  = (const float*)d_in[3];
    const float* wv  = (const float*)d_in[4];
    const float* w1  = (const float*)d_in[5];
    const float* b1  = (const float*)d_in[6];
    const float* w2  = (const float*)d_in[7];
    const float* b2  = (const float*)d_in[8];
    float* out = (float*)d_out;
    float* ws  = (float*)d_ws;

    float* part_esum = ws;               // 131072
    float* part_u    = ws + 131072;      // 131072
    float* a         = ws + 262144;      // 2048
    float* h         = ws + 264192;      // 8192
    float* spart     = ws + 272384;      // 256

    k_esum<<<dim3(64, BB), 256, 0, stream>>>(x, emb, part_esum);
    k_qsum_a<<<BB, 256, 0, stream>>>(part_esum, wq, wk, a);
    k_u<<<dim3(64, BB), 256, 0, stream>>>(x, emb, a, part_u);
    k_vout_h<<<BB, 256, 0, stream>>>(part_u, wv, w1, b1, h);
    k_logits<<<2000, 256, 0, stream>>>(h, w2, b2, out);
    k_smax1<<<dim3(16, BB), 256, 0, stream>>>(out, spart);
    k_norm<<<dim3(16, BB), 256, 0, stream>>>(spart, out);
}